// Round 7
// baseline (264.145 us; speedup 1.0000x reference)
//
#include <hip/hip_runtime.h>

// Problem constants (fixed by setup_inputs in the reference)
constexpr int B = 128;
constexpr int C = 4;          // classes; C*S = 2^18
constexpr int S = 65536;      // 2^16
constexpr int N = B * S;      // 8388608 positions
constexpr int NG = N / 4;     // float4 groups = 2097152
constexpr int NSEG = 8;
constexpr int NACC = 2 * NSEG;   // 8 seg loss-sums + 8 seg counts

constexpr int GRID  = 512;
constexpr int BLOCK = 256;
constexpr int WAVES = BLOCK / 64;          // 4
constexpr int NWAVE = GRID * WAVES;        // 2048 waves total
constexpr int TILES = NG / (NWAVE * 64);   // 16 tiles/wave, 64 groups each
static_assert(TILES * NWAVE * 64 == NG, "exact tiling");

constexpr int SEGB  = 1024;                // bytes per stream segment (64 lanes x 16B)
constexpr int TILEB = 7 * SEGB;            // 7 KB per tile (l0..l3, tg, sv, mk)
constexpr int DEPTH = 2;                   // double buffer per wave

typedef float fx4 __attribute__((ext_vector_type(4)));
typedef int   ix4 __attribute__((ext_vector_type(4)));

#define GLB(p) ((const __attribute__((address_space(1))) void*)(p))
#define LDS(p) ((__attribute__((address_space(3))) void*)(p))

// Issue the 7 LDS-DMA loads for one wave-tile.
// Lane i's 16B lands at lds_base + 16*i — exactly the 16B lane i consumes.
__device__ __forceinline__ void issue_tile(
    const float* __restrict__ input, const int* __restrict__ target,
    const int* __restrict__ seg, const float* __restrict__ mask,
    char* lb, int wave_id, int t, int lane)
{
    const int g0 = (wave_id + t * NWAVE) * 64;  // group base of this wave-tile
    const int p0 = g0 << 2;                     // position base (multiple of 256)
    const int b  = p0 >> 16;
    const int s  = p0 & (S - 1);
    const int base = (b << 18) + s;             // b*C*S + s
    const int lo = lane * 16;                   // per-lane byte offset

    __builtin_amdgcn_global_load_lds(GLB((const char*)(input + base)         + lo), LDS(lb + 0 * SEGB), 16, 0, 0);
    __builtin_amdgcn_global_load_lds(GLB((const char*)(input + base +     S) + lo), LDS(lb + 1 * SEGB), 16, 0, 0);
    __builtin_amdgcn_global_load_lds(GLB((const char*)(input + base + 2 * S) + lo), LDS(lb + 2 * SEGB), 16, 0, 0);
    __builtin_amdgcn_global_load_lds(GLB((const char*)(input + base + 3 * S) + lo), LDS(lb + 3 * SEGB), 16, 0, 0);
    __builtin_amdgcn_global_load_lds(GLB((const char*)(target + p0)          + lo), LDS(lb + 4 * SEGB), 16, 0, 0);
    __builtin_amdgcn_global_load_lds(GLB((const char*)(seg    + p0)          + lo), LDS(lb + 5 * SEGB), 16, 0, 0);
    __builtin_amdgcn_global_load_lds(GLB((const char*)(mask   + p0)          + lo), LDS(lb + 6 * SEGB), 16, 0, 0);
}

__global__ __launch_bounds__(BLOCK) void ce_partial_kernel(
    const float* __restrict__ input,   // (B, C, S)
    const int*   __restrict__ target,  // (B, S) in [0, C)
    const int*   __restrict__ seg,     // (B, S) in [0, NSEG)
    const float* __restrict__ mask,    // (B, S) in {0,1}
    float* __restrict__ pt)            // (NACC, GRID) partials
{
    // Per-wave PRIVATE double buffers: no __syncthreads in the hot loop,
    // so no forced vmcnt(0) drain — the DMA queue stays deep.
    __shared__ __align__(16) char smem[WAVES * DEPTH * TILEB];  // 56 KB
    __shared__ float red[WAVES][NACC];

    const int lane = threadIdx.x & 63;
    const int w    = threadIdx.x >> 6;
    const int wave_id = blockIdx.x * WAVES + w;
    char* mybuf = smem + w * (DEPTH * TILEB);

    float ssum[NSEG], scnt[NSEG];
#pragma unroll
    for (int k = 0; k < NSEG; ++k) { ssum[k] = 0.f; scnt[k] = 0.f; }

    // Prime the pipeline: tile 0 into buffer 0
    issue_tile(input, target, seg, mask, mybuf, wave_id, 0, lane);

#pragma unroll 1
    for (int t = 0; t < TILES; ++t) {
        if (t + 1 < TILES) {
            issue_tile(input, target, seg, mask,
                       mybuf + ((t + 1) & 1) * TILEB, wave_id, t + 1, lane);
            // Wait for tile t's 7 DMAs (oldest); tile t+1's 7 stay in flight.
            asm volatile("s_waitcnt vmcnt(7)" ::: "memory");
        } else {
            asm volatile("s_waitcnt vmcnt(0)" ::: "memory");
        }

        const char* lb = mybuf + (t & 1) * TILEB;
        const int lo = lane * 16;
        const fx4 l0 = *(const fx4*)(lb + 0 * SEGB + lo);
        const fx4 l1 = *(const fx4*)(lb + 1 * SEGB + lo);
        const fx4 l2 = *(const fx4*)(lb + 2 * SEGB + lo);
        const fx4 l3 = *(const fx4*)(lb + 3 * SEGB + lo);
        const ix4 tg = *(const ix4*)(lb + 4 * SEGB + lo);
        const ix4 sv = *(const ix4*)(lb + 5 * SEGB + lo);
        const fx4 mk = *(const fx4*)(lb + 6 * SEGB + lo);

        const float a0[4] = { l0.x, l0.y, l0.z, l0.w };
        const float a1[4] = { l1.x, l1.y, l1.z, l1.w };
        const float a2[4] = { l2.x, l2.y, l2.z, l2.w };
        const float a3[4] = { l3.x, l3.y, l3.z, l3.w };
        const int   tgv[4] = { tg.x, tg.y, tg.z, tg.w };
        const int   sgv[4] = { sv.x, sv.y, sv.z, sv.w };
        const float mkv[4] = { mk.x, mk.y, mk.z, mk.w };

#pragma unroll
        for (int j = 0; j < 4; ++j) {
            const float x0 = a0[j], x1 = a1[j], x2 = a2[j], x3 = a3[j];
            const float m = fmaxf(fmaxf(x0, x1), fmaxf(x2, x3));
            const float sum = __expf(x0 - m) + __expf(x1 - m)
                            + __expf(x2 - m) + __expf(x3 - m);
            const float lse = m + __logf(sum);
            const int tt = tgv[j];
            const float chosen = (tt == 0) ? x0 : (tt == 1) ? x1 : (tt == 2) ? x2 : x3;
            const float mval = mkv[j];
            const float loss = (lse - chosen) * mval;   // ce * mask (mask ∈ {0,1})
            const int sgj = sgv[j];
#pragma unroll
            for (int k = 0; k < NSEG; ++k) {
                const bool hit = (sgj == k);
                ssum[k] += hit ? loss : 0.f;
                scnt[k] += hit ? mval : 0.f;
            }
        }
    }

    // Wave butterfly reduction of the 16 accumulators
    float vals[NACC];
#pragma unroll
    for (int k = 0; k < NSEG; ++k) { vals[k] = ssum[k]; vals[NSEG + k] = scnt[k]; }
#pragma unroll
    for (int i = 0; i < NACC; ++i) {
        float v = vals[i];
#pragma unroll
        for (int off = 32; off > 0; off >>= 1)
            v += __shfl_xor(v, off, 64);
        vals[i] = v;
    }

    if (lane == 0) {
#pragma unroll
        for (int i = 0; i < NACC; ++i) red[w][i] = vals[i];
    }
    __syncthreads();
    if (threadIdx.x < NACC) {
        const int i = threadIdx.x;
        pt[i * GRID + blockIdx.x] =
            red[0][i] + red[1][i] + red[2][i] + red[3][i];
    }
}

// Stage 2: reduce (NACC, GRID) partials + scalar epilogue. One 512-thread block.
__global__ __launch_bounds__(512) void ce_final_kernel(
    const float* __restrict__ pt, float* __restrict__ out)
{
    const int t = threadIdx.x;            // 512 threads
    float vals[NACC];
#pragma unroll
    for (int i = 0; i < NACC; ++i) {
        float v = pt[i * GRID + t];       // GRID == 512: one strip
#pragma unroll
        for (int off = 32; off > 0; off >>= 1)
            v += __shfl_xor(v, off, 64);
        vals[i] = v;
    }

    __shared__ float red[8][NACC];
    const int wave = t >> 6;
    const int lane = t & 63;
    if (lane == 0) {
#pragma unroll
        for (int i = 0; i < NACC; ++i) red[wave][i] = vals[i];
    }
    __syncthreads();

    if (t == 0) {
        float acc[NACC];
        for (int i = 0; i < NACC; ++i) {
            float v = 0.f;
            for (int w = 0; w < 8; ++w) v += red[w][i];
            acc[i] = v;
        }

        float ssum[NSEG], scnt[NSEG];
        float tot_loss = 0.f, msum = 0.f;
        for (int k = 0; k < NSEG; ++k) {
            ssum[k] = acc[k];
            scnt[k] = acc[NSEG + k];
            tot_loss += ssum[k];
            msum += scnt[k];                       // sum(mask) == sum of counts
        }
        const float fallback = tot_loss / (float)N;   // jnp.mean(loss)

        float cl[NSEG], cc[NSEG];
        float total = 0.f;
        for (int k = 0; k < NSEG; ++k) {
            const bool has = scnt[k] > 0.f;
            cl[k] = has ? (ssum[k] / scnt[k]) : fallback;
            cc[k] = has ? scnt[k] : 1.f;
            total += cl[k] * cc[k];
        }
        float num = 0.f;
        for (int k = 0; k < NSEG; ++k) {
            const float prop = (total > 0.f) ? (cl[k] * cc[k] / total)
                                             : (1.f / (float)NSEG);
            const float w = 1.f + prop;               // WEIGHT_ALPHA = 1.0
            num += w * ssum[k];   // sum(loss*w) = sum_k w[k]*seg_sum[k]
        }
        out[0] = num / msum;                          // / sum(mask)
    }
}

extern "C" void kernel_launch(void* const* d_in, const int* in_sizes, int n_in,
                              void* d_out, int out_size, void* d_ws, size_t ws_size,
                              hipStream_t stream) {
    const float* input  = (const float*)d_in[0];
    const int*   target = (const int*)d_in[1];
    const int*   seg    = (const int*)d_in[2];
    const float* mask   = (const float*)d_in[3];
    float* pt  = (float*)d_ws;            // NACC * GRID floats = 32 KB
    float* out = (float*)d_out;

    ce_partial_kernel<<<GRID, BLOCK, 0, stream>>>(input, target, seg, mask, pt);
    ce_final_kernel<<<1, 512, 0, stream>>>(pt, out);
}

// Round 8
// 247.784 us; speedup vs baseline: 1.0660x; 1.0660x over previous
//
#include <hip/hip_runtime.h>

// Problem constants (fixed by setup_inputs in the reference)
constexpr int B = 128;
constexpr int C = 4;          // classes; C*S = 2^18
constexpr int S = 65536;      // 2^16
constexpr int N = B * S;      // 8388608 positions
constexpr int NG = N / 4;     // float4 groups = 2097152
constexpr int NSEG = 8;
constexpr int NACC = 2 * NSEG;   // 8 seg loss-sums + 8 seg counts

constexpr int GRID  = 1024;
constexpr int BLOCK = 256;
constexpr int WAVES = BLOCK / 64;          // 4
constexpr int NWAVE = GRID * WAVES;        // 4096 waves
constexpr int TILES = NG / (NWAVE * 64);   // 8 tiles/wave, 64 groups each
static_assert(TILES * NWAVE * 64 == NG, "exact tiling");

constexpr int SEGB  = 1024;                // 64 lanes x 16B per stream segment
constexpr int LSEG  = 4;                   // logit segments per tile (classes)
constexpr int TILEB = LSEG * SEGB;         // 4 KB per tile
constexpr int DEPTH = 2;                   // per-wave double buffer

typedef float fx4 __attribute__((ext_vector_type(4)));
typedef int   ix4 __attribute__((ext_vector_type(4)));

#define GLB(p) ((const __attribute__((address_space(1))) void*)(p))
#define LDS(p) ((__attribute__((address_space(3))) void*)(p))

constexpr int AUX_NT = 2;   // gfx940+ CPol: bit1 = nt (non-temporal)

// Small-stream (VGPR-path) tile data
struct Sml { ix4 tg, sv; fx4 mk; };

// Issue one wave-tile: 4 logit DMAs (NT) + 3 VGPR NT loads. 7 vmcnt events.
__device__ __forceinline__ Sml issue_tile(
    const float* __restrict__ input, const int* __restrict__ target,
    const int* __restrict__ seg, const float* __restrict__ mask,
    char* lb, int wave_id, int t, int lane)
{
    const int g0 = (wave_id + t * NWAVE) * 64;  // group base of this wave-tile
    const int p0 = g0 << 2;                     // position base (multiple of 256)
    const int b  = p0 >> 16;
    const int s  = p0 & (S - 1);
    const int base = (b << 18) + s;             // b*C*S + s
    const int lo = lane * 16;                   // per-lane byte offset

    // Logits: NT DMA direct to LDS (lane i's 16B -> lds_base + 16*i)
    __builtin_amdgcn_global_load_lds(GLB((const char*)(input + base)         + lo), LDS(lb + 0 * SEGB), 16, 0, AUX_NT);
    __builtin_amdgcn_global_load_lds(GLB((const char*)(input + base +     S) + lo), LDS(lb + 1 * SEGB), 16, 0, AUX_NT);
    __builtin_amdgcn_global_load_lds(GLB((const char*)(input + base + 2 * S) + lo), LDS(lb + 2 * SEGB), 16, 0, AUX_NT);
    __builtin_amdgcn_global_load_lds(GLB((const char*)(input + base + 3 * S) + lo), LDS(lb + 3 * SEGB), 16, 0, AUX_NT);

    // Small streams: NT loads on the VGPR-return path
    Sml r;
    const int pp = p0 + (lane << 2);            // 4 ints per lane
    r.tg = __builtin_nontemporal_load((const ix4*)(target + pp));
    r.sv = __builtin_nontemporal_load((const ix4*)(seg + pp));
    r.mk = __builtin_nontemporal_load((const fx4*)(mask + pp));
    return r;
}

__global__ __launch_bounds__(BLOCK) void ce_partial_kernel(
    const float* __restrict__ input,   // (B, C, S)
    const int*   __restrict__ target,  // (B, S) in [0, C)
    const int*   __restrict__ seg,     // (B, S) in [0, NSEG)
    const float* __restrict__ mask,    // (B, S) in {0,1}
    float* __restrict__ pt)            // (NACC, GRID) partials
{
    // Per-wave PRIVATE double buffers — no __syncthreads in the hot loop,
    // so the shared vmcnt queue never drains to 0 until the end.
    __shared__ __align__(16) char smem[WAVES * DEPTH * TILEB];  // 32 KB
    __shared__ float red[WAVES][NACC];

    const int lane = threadIdx.x & 63;
    const int w    = threadIdx.x >> 6;
    const int wave_id = blockIdx.x * WAVES + w;
    char* mybuf = smem + w * (DEPTH * TILEB);

    float ssum[NSEG], scnt[NSEG];
#pragma unroll
    for (int k = 0; k < NSEG; ++k) { ssum[k] = 0.f; scnt[k] = 0.f; }

    // Prime: tile 0 into buffer 0
    Sml cur = issue_tile(input, target, seg, mask, mybuf, wave_id, 0, lane);

#pragma unroll 1
    for (int t = 0; t < TILES; ++t) {
        Sml nxt;
        if (t + 1 < TILES) {
            nxt = issue_tile(input, target, seg, mask,
                             mybuf + ((t + 1) & 1) * TILEB, wave_id, t + 1, lane);
            // 14 vmcnt events outstanding; wait until <=7 -> tile t's 7 done
            // (vmcnt retires in issue order).
            asm volatile("s_waitcnt vmcnt(7)" ::: "memory");
        } else {
            asm volatile("s_waitcnt vmcnt(0)" ::: "memory");
        }

        const char* lb = mybuf + (t & 1) * TILEB;
        const int lo = lane * 16;
        const fx4 l0 = *(const fx4*)(lb + 0 * SEGB + lo);
        const fx4 l1 = *(const fx4*)(lb + 1 * SEGB + lo);
        const fx4 l2 = *(const fx4*)(lb + 2 * SEGB + lo);
        const fx4 l3 = *(const fx4*)(lb + 3 * SEGB + lo);

        const float a0[4] = { l0.x, l0.y, l0.z, l0.w };
        const float a1[4] = { l1.x, l1.y, l1.z, l1.w };
        const float a2[4] = { l2.x, l2.y, l2.z, l2.w };
        const float a3[4] = { l3.x, l3.y, l3.z, l3.w };
        const int   tgv[4] = { cur.tg.x, cur.tg.y, cur.tg.z, cur.tg.w };
        const int   sgv[4] = { cur.sv.x, cur.sv.y, cur.sv.z, cur.sv.w };
        const float mkv[4] = { cur.mk.x, cur.mk.y, cur.mk.z, cur.mk.w };

#pragma unroll
        for (int j = 0; j < 4; ++j) {
            const float x0 = a0[j], x1 = a1[j], x2 = a2[j], x3 = a3[j];
            const float m = fmaxf(fmaxf(x0, x1), fmaxf(x2, x3));
            const float sum = __expf(x0 - m) + __expf(x1 - m)
                            + __expf(x2 - m) + __expf(x3 - m);
            const float lse = m + __logf(sum);
            const int tt = tgv[j];
            const float chosen = (tt == 0) ? x0 : (tt == 1) ? x1 : (tt == 2) ? x2 : x3;
            const float mval = mkv[j];
            const float loss = (lse - chosen) * mval;   // ce * mask (mask ∈ {0,1})
            const int sgj = sgv[j];
#pragma unroll
            for (int k = 0; k < NSEG; ++k) {
                const bool hit = (sgj == k);
                ssum[k] += hit ? loss : 0.f;
                scnt[k] += hit ? mval : 0.f;
            }
        }
        cur = nxt;
    }

    // Wave butterfly reduction of the 16 accumulators
    float vals[NACC];
#pragma unroll
    for (int k = 0; k < NSEG; ++k) { vals[k] = ssum[k]; vals[NSEG + k] = scnt[k]; }
#pragma unroll
    for (int i = 0; i < NACC; ++i) {
        float v = vals[i];
#pragma unroll
        for (int off = 32; off > 0; off >>= 1)
            v += __shfl_xor(v, off, 64);
        vals[i] = v;
    }

    if (lane == 0) {
#pragma unroll
        for (int i = 0; i < NACC; ++i) red[w][i] = vals[i];
    }
    __syncthreads();
    if (threadIdx.x < NACC) {
        const int i = threadIdx.x;
        pt[i * GRID + blockIdx.x] =
            red[0][i] + red[1][i] + red[2][i] + red[3][i];
    }
}

// Stage 2: reduce (NACC, GRID) partials + scalar epilogue. One 1024-thread block.
__global__ __launch_bounds__(1024) void ce_final_kernel(
    const float* __restrict__ pt, float* __restrict__ out)
{
    const int t = threadIdx.x;            // 1024 threads
    float vals[NACC];
#pragma unroll
    for (int i = 0; i < NACC; ++i) {
        float v = pt[i * GRID + t];       // GRID == 1024: one strip
#pragma unroll
        for (int off = 32; off > 0; off >>= 1)
            v += __shfl_xor(v, off, 64);
        vals[i] = v;
    }

    __shared__ float red[16][NACC];
    const int wave = t >> 6;
    const int lane = t & 63;
    if (lane == 0) {
#pragma unroll
        for (int i = 0; i < NACC; ++i) red[wave][i] = vals[i];
    }
    __syncthreads();

    if (t == 0) {
        float acc[NACC];
        for (int i = 0; i < NACC; ++i) {
            float v = 0.f;
            for (int w = 0; w < 16; ++w) v += red[w][i];
            acc[i] = v;
        }

        float ssum[NSEG], scnt[NSEG];
        float tot_loss = 0.f, msum = 0.f;
        for (int k = 0; k < NSEG; ++k) {
            ssum[k] = acc[k];
            scnt[k] = acc[NSEG + k];
            tot_loss += ssum[k];
            msum += scnt[k];                       // sum(mask) == sum of counts
        }
        const float fallback = tot_loss / (float)N;   // jnp.mean(loss)

        float cl[NSEG], cc[NSEG];
        float total = 0.f;
        for (int k = 0; k < NSEG; ++k) {
            const bool has = scnt[k] > 0.f;
            cl[k] = has ? (ssum[k] / scnt[k]) : fallback;
            cc[k] = has ? scnt[k] : 1.f;
            total += cl[k] * cc[k];
        }
        float num = 0.f;
        for (int k = 0; k < NSEG; ++k) {
            const float prop = (total > 0.f) ? (cl[k] * cc[k] / total)
                                             : (1.f / (float)NSEG);
            const float w = 1.f + prop;               // WEIGHT_ALPHA = 1.0
            num += w * ssum[k];   // sum(loss*w) = sum_k w[k]*seg_sum[k]
        }
        out[0] = num / msum;                          // / sum(mask)
    }
}

extern "C" void kernel_launch(void* const* d_in, const int* in_sizes, int n_in,
                              void* d_out, int out_size, void* d_ws, size_t ws_size,
                              hipStream_t stream) {
    const float* input  = (const float*)d_in[0];
    const int*   target = (const int*)d_in[1];
    const int*   seg    = (const int*)d_in[2];
    const float* mask   = (const float*)d_in[3];
    float* pt  = (float*)d_ws;            // NACC * GRID floats = 64 KB
    float* out = (float*)d_out;

    ce_partial_kernel<<<GRID, BLOCK, 0, stream>>>(input, target, seg, mask, pt);
    ce_final_kernel<<<1, 1024, 0, stream>>>(pt, out);
}

// Round 9
// 244.270 us; speedup vs baseline: 1.0814x; 1.0144x over previous
//
#include <hip/hip_runtime.h>

// Problem constants (fixed by setup_inputs in the reference)
constexpr int B = 128;
constexpr int C = 4;          // classes; C*S = 2^18
constexpr int S = 65536;      // 2^16
constexpr int N = B * S;      // 8388608 positions
constexpr int NG = N / 4;     // float4 groups = 2097152
constexpr int NSEG = 8;
constexpr int NACC = 2 * NSEG;   // 8 seg loss-sums + 8 seg counts

constexpr int GRID  = 4096;
constexpr int BLOCK = 256;
constexpr int HALF  = NG / 2;    // each thread: group g and g + HALF
static_assert(GRID * BLOCK * 2 == NG, "two groups per thread");

// Native Clang vector types — accepted by __builtin_nontemporal_load
typedef float fx4 __attribute__((ext_vector_type(4)));
typedef int   ix4 __attribute__((ext_vector_type(4)));

struct Grp {
    fx4 l0, l1, l2, l3;   // logits, classes 0..3
    ix4 tg, sv;           // target, segment
    fx4 mk;               // mask
};

__device__ __forceinline__ Grp load_grp(
    const float* __restrict__ input, const int* __restrict__ target,
    const int* __restrict__ seg, const float* __restrict__ mask, int g)
{
    const int p = g << 2;             // flat position (b*S + s), 4-aligned
    const int b = p >> 16;            // p / S
    const int s = p & (S - 1);
    const int base = (b << 18) + s;   // b*C*S + s
    Grp r;
    r.l0 = __builtin_nontemporal_load((const fx4*)(input + base));
    r.l1 = __builtin_nontemporal_load((const fx4*)(input + base + S));
    r.l2 = __builtin_nontemporal_load((const fx4*)(input + base + 2 * S));
    r.l3 = __builtin_nontemporal_load((const fx4*)(input + base + 3 * S));
    r.tg = __builtin_nontemporal_load((const ix4*)(target + p));
    r.sv = __builtin_nontemporal_load((const ix4*)(seg + p));
    r.mk = __builtin_nontemporal_load((const fx4*)(mask + p));
    return r;
}

__device__ __forceinline__ void consume(
    const Grp& cur, float* ssum, float* scnt)
{
    const float a0[4] = { cur.l0.x, cur.l0.y, cur.l0.z, cur.l0.w };
    const float a1[4] = { cur.l1.x, cur.l1.y, cur.l1.z, cur.l1.w };
    const float a2[4] = { cur.l2.x, cur.l2.y, cur.l2.z, cur.l2.w };
    const float a3[4] = { cur.l3.x, cur.l3.y, cur.l3.z, cur.l3.w };
    const int   tgv[4] = { cur.tg.x, cur.tg.y, cur.tg.z, cur.tg.w };
    const int   sgv[4] = { cur.sv.x, cur.sv.y, cur.sv.z, cur.sv.w };
    const float mkv[4] = { cur.mk.x, cur.mk.y, cur.mk.z, cur.mk.w };

#pragma unroll
    for (int j = 0; j < 4; ++j) {
        const float x0 = a0[j], x1 = a1[j], x2 = a2[j], x3 = a3[j];
        const float m = fmaxf(fmaxf(x0, x1), fmaxf(x2, x3));
        const float sum = __expf(x0 - m) + __expf(x1 - m)
                        + __expf(x2 - m) + __expf(x3 - m);
        const float lse = m + __logf(sum);
        const int t = tgv[j];
        const float chosen = (t == 0) ? x0 : (t == 1) ? x1 : (t == 2) ? x2 : x3;
        const float mval = mkv[j];
        const float loss = (lse - chosen) * mval;   // ce * mask (mask ∈ {0,1})
        const int sgj = sgv[j];
#pragma unroll
        for (int k = 0; k < NSEG; ++k) {
            const bool hit = (sgj == k);
            ssum[k] += hit ? loss : 0.f;
            scnt[k] += hit ? mval : 0.f;
        }
    }
}

__global__ __launch_bounds__(BLOCK) void ce_partial_kernel(
    const float* __restrict__ input,   // (B, C, S)
    const int*   __restrict__ target,  // (B, S) in [0, C)
    const int*   __restrict__ seg,     // (B, S) in [0, NSEG)
    const float* __restrict__ mask,    // (B, S) in {0,1}
    float* __restrict__ pt)            // (NACC, GRID) partials
{
    const int g0 = blockIdx.x * BLOCK + threadIdx.x;

    // Issue all 14 NT loads back-to-back — deepest per-wave MLP, no
    // mid-stream waitcnt, no pipeline serialization.
    const Grp ga = load_grp(input, target, seg, mask, g0);
    const Grp gb = load_grp(input, target, seg, mask, g0 + HALF);

    float ssum[NSEG], scnt[NSEG];
#pragma unroll
    for (int k = 0; k < NSEG; ++k) { ssum[k] = 0.f; scnt[k] = 0.f; }

    consume(ga, ssum, scnt);
    consume(gb, ssum, scnt);

    // Wave (64-lane) butterfly reduction of the 16 accumulators
    float vals[NACC];
#pragma unroll
    for (int k = 0; k < NSEG; ++k) { vals[k] = ssum[k]; vals[NSEG + k] = scnt[k]; }
#pragma unroll
    for (int i = 0; i < NACC; ++i) {
        float v = vals[i];
#pragma unroll
        for (int off = 32; off > 0; off >>= 1)
            v += __shfl_xor(v, off, 64);
        vals[i] = v;
    }

    __shared__ float red[4][NACC];
    const int wave = threadIdx.x >> 6;
    const int lane = threadIdx.x & 63;
    if (lane == 0) {
#pragma unroll
        for (int i = 0; i < NACC; ++i) red[wave][i] = vals[i];
    }
    __syncthreads();
    if (threadIdx.x < NACC) {
        const int i = threadIdx.x;
        pt[i * GRID + blockIdx.x] =
            red[0][i] + red[1][i] + red[2][i] + red[3][i];
    }
}

// Stage 2: reduce (NACC, GRID) partials + scalar epilogue. One block.
__global__ __launch_bounds__(1024) void ce_final_kernel(
    const float* __restrict__ pt, float* __restrict__ out)
{
    const int t = threadIdx.x;            // 1024 threads
    float vals[NACC];
#pragma unroll
    for (int i = 0; i < NACC; ++i) {
        float v = 0.f;
#pragma unroll
        for (int k = 0; k < GRID / 1024; ++k)      // 4 coalesced strips
            v += pt[i * GRID + t + k * 1024];
#pragma unroll
        for (int off = 32; off > 0; off >>= 1)
            v += __shfl_xor(v, off, 64);
        vals[i] = v;
    }

    __shared__ float red[16][NACC];
    const int wave = t >> 6;
    const int lane = t & 63;
    if (lane == 0) {
#pragma unroll
        for (int i = 0; i < NACC; ++i) red[wave][i] = vals[i];
    }
    __syncthreads();

    if (t == 0) {
        float acc[NACC];
        for (int i = 0; i < NACC; ++i) {
            float v = 0.f;
            for (int w = 0; w < 16; ++w) v += red[w][i];
            acc[i] = v;
        }

        float ssum[NSEG], scnt[NSEG];
        float tot_loss = 0.f, msum = 0.f;
        for (int k = 0; k < NSEG; ++k) {
            ssum[k] = acc[k];
            scnt[k] = acc[NSEG + k];
            tot_loss += ssum[k];
            msum += scnt[k];                       // sum(mask) == sum of counts
        }
        const float fallback = tot_loss / (float)N;   // jnp.mean(loss)

        float cl[NSEG], cc[NSEG];
        float total = 0.f;
        for (int k = 0; k < NSEG; ++k) {
            const bool has = scnt[k] > 0.f;
            cl[k] = has ? (ssum[k] / scnt[k]) : fallback;
            cc[k] = has ? scnt[k] : 1.f;
            total += cl[k] * cc[k];
        }
        float num = 0.f;
        for (int k = 0; k < NSEG; ++k) {
            const float prop = (total > 0.f) ? (cl[k] * cc[k] / total)
                                             : (1.f / (float)NSEG);
            const float w = 1.f + prop;               // WEIGHT_ALPHA = 1.0
            num += w * ssum[k];   // sum(loss*w) = sum_k w[k]*seg_sum[k]
        }
        out[0] = num / msum;                          // / sum(mask)
    }
}

extern "C" void kernel_launch(void* const* d_in, const int* in_sizes, int n_in,
                              void* d_out, int out_size, void* d_ws, size_t ws_size,
                              hipStream_t stream) {
    const float* input  = (const float*)d_in[0];
    const int*   target = (const int*)d_in[1];
    const int*   seg    = (const int*)d_in[2];
    const float* mask   = (const float*)d_in[3];
    float* pt  = (float*)d_ws;            // NACC * GRID floats = 256 KB
    float* out = (float*)d_out;

    ce_partial_kernel<<<GRID, BLOCK, 0, stream>>>(input, target, seg, mask, pt);
    ce_final_kernel<<<1, 1024, 0, stream>>>(pt, out);
}